// Round 6
// baseline (143.487 us; speedup 1.0000x reference)
//
#include <hip/hip_runtime.h>

#define WAVE 64

typedef float v4f __attribute__((ext_vector_type(4)));
typedef int   v4i __attribute__((ext_vector_type(4)));

// ---------------------------------------------------------------------------
// Kernel A: segment start offsets from the sorted batch index, vectorized.
// seg_start[s] = min{ i : batch[i] >= s } for s in [0,B]; seg_start[B] = N.
// One int4 per thread; the quad's predecessor element comes from the
// neighbor lane via __shfl_up (only lane 0 of each wave loads it).
// Every s in [0,B] is written exactly once -> no init needed (poison-immune).
// (R1: fusing this into B as a binary search regressed +4.8 us; keep 2-kernel.)
// ---------------------------------------------------------------------------
__global__ void find_starts4_kernel(const int* __restrict__ batch,
                                    int* __restrict__ seg_start,
                                    int N, int B) {
    const int tid  = blockIdx.x * blockDim.x + threadIdx.x;
    const int lane = threadIdx.x & (WAVE - 1);
    const long long i0 = (long long)tid * 4;
    const bool in   = (i0 < N);
    const bool full = (i0 + 3 < N);

    v4i q = (v4i)(0);
    if (full) q = ((const v4i*)batch)[tid];

    // Predecessor of this quad = last element of the previous thread's quad.
    // All threads participate in the shuffle before any early exit.
    int prevw = __shfl_up(q.w, 1);

    if (!in) return;

    int prev;
    if (lane == 0) prev = (i0 == 0) ? -1 : batch[i0 - 1];
    else           prev = prevw;      // predecessor quad is always full here

    if (full) {
        int e[4] = {q.x, q.y, q.z, q.w};
        #pragma unroll
        for (int k = 0; k < 4; ++k) {
            int cur = e[k];
            for (int s = prev + 1; s <= cur; ++s) seg_start[s] = (int)(i0 + k);
            prev = cur;
        }
    } else {
        for (long long j = i0; j < N; ++j) {
            int cur = batch[j];
            for (int s = prev + 1; s <= cur; ++s) seg_start[s] = (int)j;
            prev = cur;
        }
    }

    if (i0 + 4 >= N) {  // owner of the final quad writes the tail sentinels
        for (int s = prev + 1; s <= B; ++s) seg_start[s] = N;
    }
}

// ---------------------------------------------------------------------------
// Kernel B: one wave per segment.
// R6 change: 8-slot exec-masked accumulation. Segment lengths ~Poisson(305)
// (sigma ~17.5), so 8*WAVE = 512 covers essentially every segment in ONE
// pass: 8 independent bounds-checked float4 loads issued back-to-back (avg
// 4.8 active), no serial tail with a single load in flight (the R3/R5
// structure ran its 4-deep main loop ~once, then latency-serialized the
// rest). Masked-off lanes skip the memory op (no BW cost). while-wrapper
// keeps correctness for pathological lengths.
// Then wave tree-reduction and lane 0 computes the fused MLP:
// h=[u,mean] -> leaky_relu(h@W1+b1) -> @W2+b2.
// ---------------------------------------------------------------------------
__global__ void __launch_bounds__(256)
seg_mean_mlp_kernel(const v4f* __restrict__ x,
                    const int* __restrict__ seg_start,
                    const float* __restrict__ u,
                    const float* __restrict__ W1,   // [5,5] row-major
                    const float* __restrict__ b1,   // [5]
                    const float* __restrict__ W2,   // [5]
                    const float* __restrict__ b2,   // [1]
                    float* __restrict__ out, int B) {
    const int wid  = (blockIdx.x * blockDim.x + threadIdx.x) >> 6;
    const int lane = threadIdx.x & (WAVE - 1);
    if (wid >= B) return;

    const int start = seg_start[wid];
    const int end   = seg_start[wid + 1];

    v4f acc[8];
    #pragma unroll
    for (int k = 0; k < 8; ++k) acc[k] = (v4f)(0.f);

    int i = start + lane;
    while (i < end) {
        #pragma unroll
        for (int k = 0; k < 8; ++k) {
            const int idx = i + k * WAVE;
            if (idx < end) acc[k] += x[idx];    // exec-masked, all independent
        }
        i += 8 * WAVE;
    }

    acc[0] += acc[1]; acc[2] += acc[3]; acc[4] += acc[5]; acc[6] += acc[7];
    acc[0] += acc[2]; acc[4] += acc[6];
    acc[0] += acc[4];

    float sx = acc[0].x, sy = acc[0].y, sz = acc[0].z, sw = acc[0].w;
    #pragma unroll
    for (int off = 32; off > 0; off >>= 1) {
        sx += __shfl_down(sx, off);
        sy += __shfl_down(sy, off);
        sz += __shfl_down(sz, off);
        sw += __shfl_down(sw, off);
    }

    if (lane == 0) {
        const int cnt = end - start;
        const float inv = (cnt > 0) ? (1.0f / (float)cnt) : 0.0f;

        float h[5];
        h[0] = u[wid];
        h[1] = sx * inv;
        h[2] = sy * inv;
        h[3] = sz * inv;
        h[4] = sw * inv;

        float o = b2[0];
        #pragma unroll
        for (int j = 0; j < 5; ++j) {
            float s = b1[j];
            #pragma unroll
            for (int i2 = 0; i2 < 5; ++i2) s += h[i2] * W1[i2 * 5 + j];
            s = (s > 0.0f) ? s : 0.1f * s;   // leaky_relu, slope 0.1
            o += s * W2[j];
        }
        out[wid] = o;
    }
}

extern "C" void kernel_launch(void* const* d_in, const int* in_sizes, int n_in,
                              void* d_out, int out_size, void* d_ws, size_t ws_size,
                              hipStream_t stream) {
    const float* x     = (const float*)d_in[0];  // [N,4]
    const int*   batch = (const int*)  d_in[1];  // [N]
    const float* u     = (const float*)d_in[2];  // [B,1]
    const float* W1    = (const float*)d_in[3];  // [5,5]
    const float* b1    = (const float*)d_in[4];  // [5]
    const float* W2    = (const float*)d_in[5];  // [5,1]
    const float* b2    = (const float*)d_in[6];  // [1]
    float* out = (float*)d_out;

    const int N = in_sizes[0] / 4;
    const int B = out_size;                      // output is [B,1]

    int* seg_start = (int*)d_ws;                 // [B+1] ints, fully rewritten

    const int quads = (N + 3) / 4;
    find_starts4_kernel<<<(quads + 255) / 256, 256, 0, stream>>>(batch, seg_start, N, B);

    const int threads = 256;
    const int blocks  = (int)(((long long)B * WAVE + threads - 1) / threads);
    seg_mean_mlp_kernel<<<blocks, threads, 0, stream>>>(
        (const v4f*)x, seg_start, u, W1, b1, W2, b2, out, B);
}